// Round 1
// baseline (671.104 us; speedup 1.0000x reference)
//
#include <hip/hip_runtime.h>
#include <hip/hip_bf16.h>

// GAT encoder, 2 layers, N=50000 nodes, Et=850000 edges (incl self-loops),
// IN=128, HID=OUT=256, HEADS=8, C=32.
//
// Pipeline per call:
//   CSR build by dst: hist -> scan(2-level) -> scatter
//   L1: gemm(x@W1) -> al(h,a1) -> agg(softmax+gather, +b1, ELU) -> d_out (staging)
//   L2: gemm(d_out@W2) -> al(h,a2) -> agg(+b2, ELU) -> d_out (final)
// ws usage ~58.5 MB.

#define HEADS 8
#define CPH 32   // channels per head
#define F 256    // HEADS*CPH

// ---------------- CSR build ----------------

__global__ void k_hist(const int* __restrict__ dst, int Et, int* __restrict__ deg) {
  int i = blockIdx.x * blockDim.x + threadIdx.x;
  if (i < Et) atomicAdd(&deg[dst[i]], 1);
}

__global__ __launch_bounds__(1024) void k_scan1(const int* __restrict__ deg, int n,
                                                int* __restrict__ rowptr, int* __restrict__ bsum) {
  __shared__ int s[1024];
  int i = blockIdx.x * 1024 + threadIdx.x;
  int v = (i < n) ? deg[i] : 0;
  s[threadIdx.x] = v;
  __syncthreads();
  for (int off = 1; off < 1024; off <<= 1) {
    int add = (threadIdx.x >= off) ? s[threadIdx.x - off] : 0;
    __syncthreads();
    s[threadIdx.x] += add;
    __syncthreads();
  }
  if (i < n) rowptr[i] = s[threadIdx.x] - v;   // exclusive within block
  if (threadIdx.x == 1023) bsum[blockIdx.x] = s[1023];
}

__global__ void k_scan2(const int* __restrict__ bsum, int nb, int* __restrict__ boff) {
  int t = threadIdx.x;  // 64 threads, nb <= 64
  int v = (t < nb) ? bsum[t] : 0;
  int inc = v;
  for (int off = 1; off < 64; off <<= 1) {
    int y = __shfl_up(inc, off, 64);
    if (t >= off) inc += y;
  }
  boff[t] = inc - v;    // exclusive block offsets
}

__global__ void k_scan3(int n, int Et, int* __restrict__ rowptr, const int* __restrict__ boff) {
  int i = blockIdx.x * blockDim.x + threadIdx.x;
  if (i < n) rowptr[i] += boff[i >> 10];
  if (i == 0) rowptr[n] = Et;
}

__global__ void k_fill(const int* __restrict__ src, const int* __restrict__ dst, int Et,
                       const int* __restrict__ rowptr, int* __restrict__ fill,
                       int* __restrict__ csr_src) {
  int i = blockIdx.x * blockDim.x + threadIdx.x;
  if (i < Et) {
    int d = dst[i];
    int pos = rowptr[d] + atomicAdd(&fill[d], 1);
    csr_src[pos] = src[i];
  }
}

// ---------------- GEMM: C[M,256] = A[M,K] @ B[K,256] ----------------
// 64x64 tile, 256 threads, 4x4 micro-tile, BK=16.

__global__ __launch_bounds__(256) void k_gemm(const float* __restrict__ A,
                                              const float* __restrict__ B,
                                              float* __restrict__ C, int M, int K) {
  __shared__ __align__(16) float As[16][68];  // [k][row], pad 68: 68*4=272=16*17 keeps f4 align
  __shared__ __align__(16) float Bs[16][64];  // [k][col]
  int tid = threadIdx.x;
  int tx = tid & 15, ty = tid >> 4;
  int rowBase = blockIdx.x * 64;
  int colBase = blockIdx.y * 64;
  float acc[4][4] = {};

  int arow = tid >> 2;                 // 0..63
  int akoff = (tid & 3) * 4;           // 0,4,8,12
  int arow_g = min(rowBase + arow, M - 1);
  int bk = tid >> 4;                   // 0..15
  int bc = (tid & 15) * 4;             // 0..60

  for (int k0 = 0; k0 < K; k0 += 16) {
    float4 av = *(const float4*)&A[(size_t)arow_g * K + k0 + akoff];
    float4 bv = *(const float4*)&B[(size_t)(k0 + bk) * F + colBase + bc];
    As[akoff + 0][arow] = av.x;
    As[akoff + 1][arow] = av.y;
    As[akoff + 2][arow] = av.z;
    As[akoff + 3][arow] = av.w;
    *(float4*)&Bs[bk][bc] = bv;
    __syncthreads();
#pragma unroll
    for (int k = 0; k < 16; ++k) {
      float4 a = *(const float4*)&As[k][ty * 4];
      float4 b = *(const float4*)&Bs[k][tx * 4];
      float ar[4] = {a.x, a.y, a.z, a.w};
      float br[4] = {b.x, b.y, b.z, b.w};
#pragma unroll
      for (int i = 0; i < 4; ++i)
#pragma unroll
        for (int j = 0; j < 4; ++j) acc[i][j] += ar[i] * br[j];
    }
    __syncthreads();
  }
#pragma unroll
  for (int i = 0; i < 4; ++i) {
    int r = rowBase + ty * 4 + i;
    if (r < M) {
      float4 o = make_float4(acc[i][0], acc[i][1], acc[i][2], acc[i][3]);
      *(float4*)&C[(size_t)r * F + colBase + tx * 4] = o;
    }
  }
}

// ---------------- attention logits: al_s/al_d [n,8] ----------------

__global__ __launch_bounds__(256) void k_al(const float* __restrict__ h,
                                            const float* __restrict__ a_src,
                                            const float* __restrict__ a_dst,
                                            float* __restrict__ al_s, float* __restrict__ al_d) {
  int node = blockIdx.x;
  int tid = threadIdx.x;            // 256 = 8 heads x 32 ch
  float v = h[(size_t)node * F + tid];
  int hh = tid >> 5, c = tid & 31;
  float ps = v * a_src[hh * CPH + c];
  float pd = v * a_dst[hh * CPH + c];
  for (int off = 16; off; off >>= 1) {
    ps += __shfl_down(ps, off, 32);
    pd += __shfl_down(pd, off, 32);
  }
  if (c == 0) {
    al_s[node * HEADS + hh] = ps;
    al_d[node * HEADS + hh] = pd;
  }
}

// ---------------- segmented softmax + aggregate (+bias, ELU) ----------------
// one block (256 thr) per dst node; 8 half-wave groups of 32 handle the 8 heads.

__global__ __launch_bounds__(256) void k_agg(const int* __restrict__ rowptr,
                                             const int* __restrict__ csr_src,
                                             const float* __restrict__ al_s,
                                             const float* __restrict__ al_d,
                                             const float* __restrict__ h,
                                             const float* __restrict__ bias,
                                             float* __restrict__ out) {
  int n = blockIdx.x;
  int tid = threadIdx.x;
  int base = rowptr[n];
  int d = rowptr[n + 1] - base;
  __shared__ float m_s[HEADS], inv_s[HEADS];
  __shared__ float p_s[64][HEADS];
  __shared__ int srcs[64];
  int hg = tid >> 5, slot = tid & 31;
  float ald = al_d[n * HEADS + hg];

  // pass 0: segment max per head
  float mx = -1e30f;
  for (int j = slot; j < d; j += 32) {
    int s = csr_src[base + j];
    float e = al_s[s * HEADS + hg] + ald;
    e = (e > 0.f) ? e : 0.2f * e;
    mx = fmaxf(mx, e);
  }
  for (int off = 16; off; off >>= 1) mx = fmaxf(mx, __shfl_down(mx, off, 32));
  if (slot == 0) m_s[hg] = mx;
  __syncthreads();
  float mh = m_s[hg];

  // pass 1: sum of exp
  float sm = 0.f;
  for (int j = slot; j < d; j += 32) {
    int s = csr_src[base + j];
    float e = al_s[s * HEADS + hg] + ald;
    e = (e > 0.f) ? e : 0.2f * e;
    sm += expf(e - mh);
  }
  for (int off = 16; off; off >>= 1) sm += __shfl_down(sm, off, 32);
  if (slot == 0) inv_s[hg] = 1.f / (sm + 1e-16f);
  __syncthreads();

  // pass 2: weighted gather-accumulate, chunked through LDS
  float acc = 0.f;
  for (int c0 = 0; c0 < d; c0 += 64) {
    int cn = min(64, d - c0);
    __syncthreads();  // protect p_s/srcs reuse across chunks
    for (int idx = tid; idx < cn * HEADS; idx += 256) {
      int j = idx >> 3, hh = idx & 7;
      int s = csr_src[base + c0 + j];
      if (hh == 0) srcs[j] = s;
      float e = al_s[s * HEADS + hh] + al_d[n * HEADS + hh];
      e = (e > 0.f) ? e : 0.2f * e;
      p_s[j][hh] = expf(e - m_s[hh]) * inv_s[hh];
    }
    __syncthreads();
    for (int j = 0; j < cn; ++j) {
      acc += p_s[j][hg] * h[(size_t)srcs[j] * F + tid];  // coalesced 1KB row gather
    }
  }
  float o = acc + bias[tid];
  out[(size_t)n * F + tid] = (o > 0.f) ? o : expm1f(o);
}

// ---------------- launch ----------------

extern "C" void kernel_launch(void* const* d_in, const int* in_sizes, int n_in,
                              void* d_out, int out_size, void* d_ws, size_t ws_size,
                              hipStream_t stream) {
  const float* x   = (const float*)d_in[0];
  const int*   ei  = (const int*)d_in[1];   // [2, Et] int32 (jax x64 disabled)
  const float* W1  = (const float*)d_in[2];
  const float* a1s = (const float*)d_in[3];
  const float* a1d = (const float*)d_in[4];
  const float* b1  = (const float*)d_in[5];
  const float* W2  = (const float*)d_in[6];
  const float* a2s = (const float*)d_in[7];
  const float* a2d = (const float*)d_in[8];
  const float* b2  = (const float*)d_in[9];

  int n  = in_sizes[0] / 128;   // 50000
  int Et = in_sizes[1] / 2;     // 850000
  const int* srcp = ei;
  const int* dstp = ei + Et;

  char* ws = (char*)d_ws;
  auto alloc = [&](size_t bytes) {
    char* p = ws;
    ws += (bytes + 255) & ~(size_t)255;
    return p;
  };
  float* hbuf   = (float*)alloc((size_t)n * F * 4);   // 51.2 MB
  float* als    = (float*)alloc((size_t)n * HEADS * 4);
  float* ald    = (float*)alloc((size_t)n * HEADS * 4);
  int*   deg    = (int*)alloc((size_t)n * 4);
  int*   fill   = (int*)alloc((size_t)n * 4);
  int*   rowptr = (int*)alloc((size_t)(n + 1) * 4);
  int*   bsum   = (int*)alloc(64 * 4);
  int*   boff   = (int*)alloc(64 * 4);
  int*   csr    = (int*)alloc((size_t)Et * 4);
  float* out1   = (float*)d_out;  // layer-1 output staged in d_out (safe: agg2 reads only hbuf)
  float* outF   = (float*)d_out;

  hipMemsetAsync(deg, 0, (size_t)n * 4, stream);
  hipMemsetAsync(fill, 0, (size_t)n * 4, stream);

  int eb = (Et + 255) / 256;
  k_hist<<<eb, 256, 0, stream>>>(dstp, Et, deg);
  int nb = (n + 1023) / 1024;
  k_scan1<<<nb, 1024, 0, stream>>>(deg, n, rowptr, bsum);
  k_scan2<<<1, 64, 0, stream>>>(bsum, nb, boff);
  k_scan3<<<(n + 255) / 256, 256, 0, stream>>>(n, Et, rowptr, boff);
  k_fill<<<eb, 256, 0, stream>>>(srcp, dstp, Et, rowptr, fill, csr);

  dim3 gg((n + 63) / 64, 4);
  // layer 1
  k_gemm<<<gg, 256, 0, stream>>>(x, W1, hbuf, n, 128);
  k_al<<<n, 256, 0, stream>>>(hbuf, a1s, a1d, als, ald);
  k_agg<<<n, 256, 0, stream>>>(rowptr, csr, als, ald, hbuf, b1, out1);
  // layer 2
  k_gemm<<<gg, 256, 0, stream>>>(out1, W2, hbuf, n, 256);
  k_al<<<n, 256, 0, stream>>>(hbuf, a2s, a2d, als, ald);
  k_agg<<<n, 256, 0, stream>>>(rowptr, csr, als, ald, hbuf, b2, outF);
}

// Round 2
// 520.339 us; speedup vs baseline: 1.2897x; 1.2897x over previous
//
#include <hip/hip_runtime.h>
#include <hip/hip_bf16.h>

// GAT encoder, 2 layers, N=50000, Et=850000, IN=128, HID=OUT=256, HEADS=8, C=32.
// fp16 activations + MFMA f16 GEMM; f32 softmax/accumulate.

#define HEADS 8
#define F 256

typedef _Float16 h8 __attribute__((ext_vector_type(8)));
typedef _Float16 h4 __attribute__((ext_vector_type(4)));
typedef float f4 __attribute__((ext_vector_type(4)));

// ---------------- conversions ----------------

__global__ void k_cvt(const float* __restrict__ in, _Float16* __restrict__ out, int n) {
  int i = blockIdx.x * blockDim.x + threadIdx.x;
  int idx = i * 4;
  if (idx < n) {
    float4 v = *(const float4*)&in[idx];
    h4 o = {(_Float16)v.x, (_Float16)v.y, (_Float16)v.z, (_Float16)v.w};
    *(h4*)&out[idx] = o;
  }
}

// W [K][N] f32 -> Wt [N][K] fp16 (transpose so GEMM B-stage reads are contiguous)
__global__ void k_cvt_wt(const float* __restrict__ W, _Float16* __restrict__ Wt, int K) {
  int k = blockIdx.x, n = threadIdx.x;  // N == 256
  Wt[(size_t)n * K + k] = (_Float16)W[(size_t)k * F + n];
}

// ---------------- CSR build ----------------

__global__ void k_hist(const int* __restrict__ dst, int Et, int* __restrict__ deg) {
  int i = blockIdx.x * blockDim.x + threadIdx.x;
  if (i < Et) atomicAdd(&deg[dst[i]], 1);
}

__global__ __launch_bounds__(1024) void k_scan1(const int* __restrict__ deg, int n,
                                                int* __restrict__ rowptr, int* __restrict__ bsum) {
  __shared__ int s[1024];
  int i = blockIdx.x * 1024 + threadIdx.x;
  int v = (i < n) ? deg[i] : 0;
  s[threadIdx.x] = v;
  __syncthreads();
  for (int off = 1; off < 1024; off <<= 1) {
    int add = (threadIdx.x >= off) ? s[threadIdx.x - off] : 0;
    __syncthreads();
    s[threadIdx.x] += add;
    __syncthreads();
  }
  if (i < n) rowptr[i] = s[threadIdx.x] - v;
  if (threadIdx.x == 1023) bsum[blockIdx.x] = s[1023];
}

__global__ void k_scan2(const int* __restrict__ bsum, int nb, int* __restrict__ boff) {
  int t = threadIdx.x;
  int v = (t < nb) ? bsum[t] : 0;
  int inc = v;
  for (int off = 1; off < 64; off <<= 1) {
    int y = __shfl_up(inc, off, 64);
    if (t >= off) inc += y;
  }
  boff[t] = inc - v;
}

__global__ void k_scan3(int n, int Et, int* __restrict__ rowptr, const int* __restrict__ boff) {
  int i = blockIdx.x * blockDim.x + threadIdx.x;
  if (i < n) rowptr[i] += boff[i >> 10];
  if (i == 0) rowptr[n] = Et;
}

__global__ void k_fill(const int* __restrict__ src, const int* __restrict__ dst, int Et,
                       const int* __restrict__ rowptr, int* __restrict__ fill,
                       int* __restrict__ csr_src) {
  int i = blockIdx.x * blockDim.x + threadIdx.x;
  if (i < Et) {
    int d = dst[i];
    int pos = rowptr[d] + atomicAdd(&fill[d], 1);
    csr_src[pos] = src[i];
  }
}

// ---------------- MFMA GEMM: C[M,256] = A[M,K] @ B[K,256] ----------------
// A fp16 row-major, Bt fp16 [256][K] (B transposed), C fp16.
// 64x64 tile, 4 waves (2x2), each wave 32x32 = 2x2 fragments of 16x16x32.

__global__ __launch_bounds__(256) void k_gemm(const _Float16* __restrict__ A,
                                              const _Float16* __restrict__ Bt,
                                              _Float16* __restrict__ C, int M, int K) {
  __shared__ _Float16 As[64][40];  // +8 pad: 80B row stride -> 2-way-free banks
  __shared__ _Float16 Bs[64][40];  // [n_local][k]
  int tid = threadIdx.x;
  int lane = tid & 63, wid = tid >> 6;
  int wr = wid >> 1, wc = wid & 1;
  int rowBase = blockIdx.x * 64, colBase = blockIdx.y * 64;
  f4 acc[2][2] = {};

  int srow = tid >> 2;             // 0..63
  int skoff = (tid & 3) * 8;       // 0,8,16,24 halfs
  int arow_g = min(rowBase + srow, M - 1);
  const _Float16* Ap = A + (size_t)arow_g * K + skoff;
  const _Float16* Bp = Bt + (size_t)(colBase + srow) * K + skoff;

  int kl = (lane >> 4) * 8;        // fragment k-offset: contiguous 8 per lane group
  int rl = lane & 15;

  for (int k0 = 0; k0 < K; k0 += 32) {
    h8 av = *(const h8*)(Ap + k0);
    h8 bv = *(const h8*)(Bp + k0);
    *(h8*)&As[srow][skoff] = av;
    *(h8*)&Bs[srow][skoff] = bv;
    __syncthreads();
    h8 a0 = *(const h8*)&As[wr * 32 + rl][kl];
    h8 a1 = *(const h8*)&As[wr * 32 + 16 + rl][kl];
    h8 b0 = *(const h8*)&Bs[wc * 32 + rl][kl];
    h8 b1 = *(const h8*)&Bs[wc * 32 + 16 + rl][kl];
    acc[0][0] = __builtin_amdgcn_mfma_f32_16x16x32_f16(a0, b0, acc[0][0], 0, 0, 0);
    acc[0][1] = __builtin_amdgcn_mfma_f32_16x16x32_f16(a0, b1, acc[0][1], 0, 0, 0);
    acc[1][0] = __builtin_amdgcn_mfma_f32_16x16x32_f16(a1, b0, acc[1][0], 0, 0, 0);
    acc[1][1] = __builtin_amdgcn_mfma_f32_16x16x32_f16(a1, b1, acc[1][1], 0, 0, 0);
    __syncthreads();
  }

  int colL = lane & 15;
  int rquad = (lane >> 4) * 4;
#pragma unroll
  for (int fi = 0; fi < 2; ++fi)
#pragma unroll
    for (int fj = 0; fj < 2; ++fj) {
      int col = colBase + wc * 32 + fj * 16 + colL;
#pragma unroll
      for (int r = 0; r < 4; ++r) {
        int row = rowBase + wr * 32 + fi * 16 + rquad + r;
        if (row < M) C[(size_t)row * F + col] = (_Float16)acc[fi][fj][r];
      }
    }
}

// ---------------- attention logits ----------------

__global__ __launch_bounds__(256) void k_al(const _Float16* __restrict__ h,
                                            const float* __restrict__ a_src,
                                            const float* __restrict__ a_dst,
                                            float* __restrict__ al_s, float* __restrict__ al_d) {
  int node = blockIdx.x;
  int tid = threadIdx.x;
  float v = (float)h[(size_t)node * F + tid];
  int hh = tid >> 5, c = tid & 31;
  float ps = v * a_src[hh * 32 + c];
  float pd = v * a_dst[hh * 32 + c];
  for (int off = 16; off; off >>= 1) {
    ps += __shfl_down(ps, off, 32);
    pd += __shfl_down(pd, off, 32);
  }
  if (c == 0) {
    al_s[node * HEADS + hh] = ps;
    al_d[node * HEADS + hh] = pd;
  }
}

// ---------------- segmented softmax + aggregate (+bias, ELU) ----------------

template <bool F16OUT>
__global__ __launch_bounds__(256) void k_agg(const int* __restrict__ rowptr,
                                             const int* __restrict__ csr_src,
                                             const float* __restrict__ al_s,
                                             const float* __restrict__ al_d,
                                             const _Float16* __restrict__ h,
                                             const float* __restrict__ bias,
                                             float* __restrict__ outf,
                                             _Float16* __restrict__ outh) {
  int n = blockIdx.x;
  int tid = threadIdx.x;
  int base = rowptr[n];
  int d = rowptr[n + 1] - base;
  int hg = tid >> 5, slot = tid & 31;
  __shared__ float e_s[64][8];
  __shared__ int srcs[64];
  __shared__ float s_s[8], m_s[8];
  float acc = 0.f, invs;

  if (d <= 64) {
    // stage leaky-relu'd logits once
    for (int idx = tid; idx < (d << 3); idx += 256) {
      int j = idx >> 3, hh = idx & 7;
      int s = csr_src[base + j];
      if (hh == 0) srcs[j] = s;
      float e = al_s[s * HEADS + hh] + al_d[n * HEADS + hh];
      e_s[j][hh] = (e > 0.f) ? e : 0.2f * e;
    }
    __syncthreads();
    float mx = -1e30f;
    for (int j = slot; j < d; j += 32) mx = fmaxf(mx, e_s[j][hg]);
    for (int off = 16; off; off >>= 1) mx = fmaxf(mx, __shfl_down(mx, off, 32));
    mx = __shfl(mx, 0, 32);
    float sm = 0.f;
    for (int j = slot; j < d; j += 32) {
      float p = __expf(e_s[j][hg] - mx);
      e_s[j][hg] = p;
      sm += p;
    }
    for (int off = 16; off; off >>= 1) sm += __shfl_down(sm, off, 32);
    if (slot == 0) s_s[hg] = sm;
    __syncthreads();  // also makes e_s p-values visible block-wide
    invs = 1.f / (s_s[hg] + 1e-16f);
    for (int j = 0; j < d; ++j) {
      acc += e_s[j][hg] * (float)h[(size_t)srcs[j] * F + tid];
    }
  } else {
    // general path (rare): 3-pass with chunked gather
    float mx = -1e30f;
    for (int j = slot; j < d; j += 32) {
      int s = csr_src[base + j];
      float e = al_s[s * HEADS + hg] + al_d[n * HEADS + hg];
      e = (e > 0.f) ? e : 0.2f * e;
      mx = fmaxf(mx, e);
    }
    for (int off = 16; off; off >>= 1) mx = fmaxf(mx, __shfl_down(mx, off, 32));
    mx = __shfl(mx, 0, 32);
    if (slot == 0) m_s[hg] = mx;
    float sm = 0.f;
    for (int j = slot; j < d; j += 32) {
      int s = csr_src[base + j];
      float e = al_s[s * HEADS + hg] + al_d[n * HEADS + hg];
      e = (e > 0.f) ? e : 0.2f * e;
      sm += __expf(e - mx);
    }
    for (int off = 16; off; off >>= 1) sm += __shfl_down(sm, off, 32);
    if (slot == 0) s_s[hg] = sm;
    __syncthreads();
    invs = 1.f / (s_s[hg] + 1e-16f);
    for (int c0 = 0; c0 < d; c0 += 64) {
      int cn = min(64, d - c0);
      __syncthreads();
      for (int idx = tid; idx < (cn << 3); idx += 256) {
        int j = idx >> 3, hh = idx & 7;
        int s = csr_src[base + c0 + j];
        if (hh == 0) srcs[j] = s;
        float e = al_s[s * HEADS + hh] + al_d[n * HEADS + hh];
        e = (e > 0.f) ? e : 0.2f * e;
        e_s[j][hh] = __expf(e - m_s[hh]);
      }
      __syncthreads();
      for (int j = 0; j < cn; ++j) {
        acc += e_s[j][hg] * (float)h[(size_t)srcs[j] * F + tid];
      }
    }
  }

  float o = acc * invs + bias[tid];
  o = (o > 0.f) ? o : expm1f(o);
  if (F16OUT) outh[(size_t)n * F + tid] = (_Float16)o;
  else outf[(size_t)n * F + tid] = o;
}

// ---------------- launch ----------------

extern "C" void kernel_launch(void* const* d_in, const int* in_sizes, int n_in,
                              void* d_out, int out_size, void* d_ws, size_t ws_size,
                              hipStream_t stream) {
  const float* x   = (const float*)d_in[0];
  const int*   ei  = (const int*)d_in[1];
  const float* W1  = (const float*)d_in[2];
  const float* a1s = (const float*)d_in[3];
  const float* a1d = (const float*)d_in[4];
  const float* b1  = (const float*)d_in[5];
  const float* W2  = (const float*)d_in[6];
  const float* a2s = (const float*)d_in[7];
  const float* a2d = (const float*)d_in[8];
  const float* b2  = (const float*)d_in[9];

  int n  = in_sizes[0] / 128;   // 50000
  int Et = in_sizes[1] / 2;     // 850000
  const int* srcp = ei;
  const int* dstp = ei + Et;

  char* ws = (char*)d_ws;
  auto alloc = [&](size_t bytes) {
    char* p = ws;
    ws += (bytes + 255) & ~(size_t)255;
    return p;
  };
  _Float16* xh     = (_Float16*)alloc((size_t)n * 128 * 2);  // 12.8 MB
  _Float16* hbuf   = (_Float16*)alloc((size_t)n * F * 2);    // 25.6 MB
  _Float16* Wt1    = (_Float16*)alloc((size_t)128 * F * 2);
  _Float16* Wt2    = (_Float16*)alloc((size_t)F * F * 2);
  float*    als    = (float*)alloc((size_t)n * HEADS * 4);
  float*    ald    = (float*)alloc((size_t)n * HEADS * 4);
  int*      deg    = (int*)alloc((size_t)n * 4);
  int*      fill   = (int*)alloc((size_t)n * 4);
  int*      rowptr = (int*)alloc((size_t)(n + 1) * 4);
  int*      bsum   = (int*)alloc(64 * 4);
  int*      boff   = (int*)alloc(64 * 4);
  int*      csr    = (int*)alloc((size_t)Et * 4);
  _Float16* out1h  = (_Float16*)d_out;  // layer-1 fp16 staged in d_out (safe: agg2 reads only hbuf)
  float*    outF   = (float*)d_out;

  hipMemsetAsync(deg, 0, (size_t)n * 4, stream);
  hipMemsetAsync(fill, 0, (size_t)n * 4, stream);

  // conversions
  k_cvt<<<(n * 128 / 4 + 255) / 256, 256, 0, stream>>>(x, xh, n * 128);
  k_cvt_wt<<<128, 256, 0, stream>>>(W1, Wt1, 128);
  k_cvt_wt<<<256, 256, 0, stream>>>(W2, Wt2, 256);

  // CSR build
  int eb = (Et + 255) / 256;
  k_hist<<<eb, 256, 0, stream>>>(dstp, Et, deg);
  int nb = (n + 1023) / 1024;
  k_scan1<<<nb, 1024, 0, stream>>>(deg, n, rowptr, bsum);
  k_scan2<<<1, 64, 0, stream>>>(bsum, nb, boff);
  k_scan3<<<(n + 255) / 256, 256, 0, stream>>>(n, Et, rowptr, boff);
  k_fill<<<eb, 256, 0, stream>>>(srcp, dstp, Et, rowptr, fill, csr);

  dim3 gg((n + 63) / 64, 4);
  // layer 1
  k_gemm<<<gg, 256, 0, stream>>>(xh, Wt1, hbuf, n, 128);
  k_al<<<n, 256, 0, stream>>>(hbuf, a1s, a1d, als, ald);
  k_agg<true><<<n, 256, 0, stream>>>(rowptr, csr, als, ald, hbuf, b1, nullptr, out1h);
  // layer 2
  k_gemm<<<gg, 256, 0, stream>>>(out1h, Wt2, hbuf, n, 256);
  k_al<<<n, 256, 0, stream>>>(hbuf, a2s, a2d, als, ald);
  k_agg<false><<<n, 256, 0, stream>>>(rowptr, csr, als, ald, hbuf, b2, outF, nullptr);
}

// Round 3
// 393.892 us; speedup vs baseline: 1.7038x; 1.3210x over previous
//
#include <hip/hip_runtime.h>
#include <hip/hip_bf16.h>

// GAT encoder, 2 layers, N=50000, Et=850000, IN=128, HID=OUT=256, HEADS=8, C=32.
// fp16 activations + MFMA f16 GEMM (al_s/al_d fused in epilogue);
// wave-per-node segmented softmax + gather aggregation.

#define HEADS 8
#define F 256

typedef _Float16 h8 __attribute__((ext_vector_type(8)));
typedef _Float16 h4 __attribute__((ext_vector_type(4)));
typedef float f4 __attribute__((ext_vector_type(4)));

#define WAVE_SYNC() do { __builtin_amdgcn_wave_barrier(); \
  asm volatile("s_waitcnt lgkmcnt(0)" ::: "memory"); \
  __builtin_amdgcn_wave_barrier(); } while (0)

// ---------------- conversions ----------------

__global__ void k_cvt(const float* __restrict__ in, _Float16* __restrict__ out, int n) {
  int i = blockIdx.x * blockDim.x + threadIdx.x;
  int idx = i * 4;
  if (idx < n) {
    float4 v = *(const float4*)&in[idx];
    h4 o = {(_Float16)v.x, (_Float16)v.y, (_Float16)v.z, (_Float16)v.w};
    *(h4*)&out[idx] = o;
  }
}

// W [K][256] f32 -> Wt [256][K] fp16
__global__ void k_cvt_wt(const float* __restrict__ W, _Float16* __restrict__ Wt, int K) {
  int k = blockIdx.x, n = threadIdx.x;
  Wt[(size_t)n * K + k] = (_Float16)W[(size_t)k * F + n];
}

// ---------------- CSR build ----------------

__global__ void k_hist(const int* __restrict__ dst, int Et, int* __restrict__ deg) {
  int i = blockIdx.x * blockDim.x + threadIdx.x;
  if (i < Et) atomicAdd(&deg[dst[i]], 1);
}

__global__ __launch_bounds__(1024) void k_scan1(const int* __restrict__ deg, int n,
                                                int* __restrict__ rowptr, int* __restrict__ bsum) {
  __shared__ int s[1024];
  int i = blockIdx.x * 1024 + threadIdx.x;
  int v = (i < n) ? deg[i] : 0;
  s[threadIdx.x] = v;
  __syncthreads();
  for (int off = 1; off < 1024; off <<= 1) {
    int add = (threadIdx.x >= off) ? s[threadIdx.x - off] : 0;
    __syncthreads();
    s[threadIdx.x] += add;
    __syncthreads();
  }
  if (i < n) rowptr[i] = s[threadIdx.x] - v;
  if (threadIdx.x == 1023) bsum[blockIdx.x] = s[1023];
}

__global__ void k_scan2(const int* __restrict__ bsum, int nb, int* __restrict__ boff) {
  int t = threadIdx.x;
  int v = (t < nb) ? bsum[t] : 0;
  int inc = v;
  for (int off = 1; off < 64; off <<= 1) {
    int y = __shfl_up(inc, off, 64);
    if (t >= off) inc += y;
  }
  boff[t] = inc - v;
}

__global__ void k_scan3(int n, int Et, int* __restrict__ rowptr, const int* __restrict__ boff) {
  int i = blockIdx.x * blockDim.x + threadIdx.x;
  if (i < n) rowptr[i] += boff[i >> 10];
  if (i == 0) rowptr[n] = Et;
}

__global__ void k_fill(const int* __restrict__ src, const int* __restrict__ dst, int Et,
                       const int* __restrict__ rowptr, int* __restrict__ fill,
                       int* __restrict__ csr_src) {
  int i = blockIdx.x * blockDim.x + threadIdx.x;
  if (i < Et) {
    int d = dst[i];
    int pos = rowptr[d] + atomicAdd(&fill[d], 1);
    csr_src[pos] = src[i];
  }
}

// ---------------- MFMA GEMM + fused attention-logit epilogue ----------------
// C[M,256] = A[M,K] @ B[K,256]; als/ald[row,head] = sum_c C[row,head*32+c]*a[head,c]
// 64x64 tile, 4 waves (2x2), wave = 32x32 = 2x2 fragments of 16x16x32.

__global__ __launch_bounds__(256) void k_gemm(const _Float16* __restrict__ A,
                                              const _Float16* __restrict__ Bt,
                                              _Float16* __restrict__ C,
                                              const float* __restrict__ a_src,
                                              const float* __restrict__ a_dst,
                                              float* __restrict__ als,
                                              float* __restrict__ ald,
                                              int M, int K) {
  __shared__ _Float16 As[64][40];
  __shared__ _Float16 Bs[64][40];
  int tid = threadIdx.x;
  int lane = tid & 63, wid = tid >> 6;
  int wr = wid >> 1, wc = wid & 1;
  int rowBase = blockIdx.x * 64, colBase = blockIdx.y * 64;
  f4 acc[2][2] = {};

  int srow = tid >> 2;
  int skoff = (tid & 3) * 8;
  int arow_g = min(rowBase + srow, M - 1);
  const _Float16* Ap = A + (size_t)arow_g * K + skoff;
  const _Float16* Bp = Bt + (size_t)(colBase + srow) * K + skoff;

  int kl = (lane >> 4) * 8;
  int rl = lane & 15;

  for (int k0 = 0; k0 < K; k0 += 32) {
    h8 av = *(const h8*)(Ap + k0);
    h8 bv = *(const h8*)(Bp + k0);
    *(h8*)&As[srow][skoff] = av;
    *(h8*)&Bs[srow][skoff] = bv;
    __syncthreads();
    h8 a0 = *(const h8*)&As[wr * 32 + rl][kl];
    h8 a1 = *(const h8*)&As[wr * 32 + 16 + rl][kl];
    h8 b0 = *(const h8*)&Bs[wc * 32 + rl][kl];
    h8 b1 = *(const h8*)&Bs[wc * 32 + 16 + rl][kl];
    acc[0][0] = __builtin_amdgcn_mfma_f32_16x16x32_f16(a0, b0, acc[0][0], 0, 0, 0);
    acc[0][1] = __builtin_amdgcn_mfma_f32_16x16x32_f16(a0, b1, acc[0][1], 0, 0, 0);
    acc[1][0] = __builtin_amdgcn_mfma_f32_16x16x32_f16(a1, b0, acc[1][0], 0, 0, 0);
    acc[1][1] = __builtin_amdgcn_mfma_f32_16x16x32_f16(a1, b1, acc[1][1], 0, 0, 0);
    __syncthreads();
  }

  int colL = lane & 15;
  int rquad = (lane >> 4) * 4;

  // C store (fp16)
#pragma unroll
  for (int fi = 0; fi < 2; ++fi)
#pragma unroll
    for (int fj = 0; fj < 2; ++fj) {
      int col = colBase + wc * 32 + fj * 16 + colL;
#pragma unroll
      for (int r = 0; r < 4; ++r) {
        int row = rowBase + wr * 32 + fi * 16 + rquad + r;
        if (row < M) C[(size_t)row * F + col] = (_Float16)acc[fi][fj][r];
      }
    }

  // fused al_s/al_d: this wave's 64 cols = head (blockIdx.y*2 + wc), c = fj*16+colL
  int head = blockIdx.y * 2 + wc;
  float as0 = a_src[head * 32 + colL];
  float as1 = a_src[head * 32 + 16 + colL];
  float ad0 = a_dst[head * 32 + colL];
  float ad1 = a_dst[head * 32 + 16 + colL];
#pragma unroll
  for (int fi = 0; fi < 2; ++fi)
#pragma unroll
    for (int r = 0; r < 4; ++r) {
      float vs = acc[fi][0][r] * as0 + acc[fi][1][r] * as1;
      float vd = acc[fi][0][r] * ad0 + acc[fi][1][r] * ad1;
#pragma unroll
      for (int off = 8; off; off >>= 1) {
        vs += __shfl_xor(vs, off);
        vd += __shfl_xor(vd, off);
      }
      int row = rowBase + wr * 32 + fi * 16 + rquad + r;
      if (colL == 0 && row < M) {
        als[row * HEADS + head] = vs;
        ald[row * HEADS + head] = vd;
      }
    }
}

// ---------------- wave-per-node softmax + aggregate (+bias, ELU) ----------------
// 256 threads = 4 waves = 4 nodes. Lane layout:
//   softmax: head hh = lane>>3, slot = lane&7 (8 heads x 8 edge-slots)
//   gather:  lane owns channels lane*4..lane*4+3 (head = lane>>3, consistent)

template <bool F16OUT>
__global__ __launch_bounds__(256) void k_agg(const int* __restrict__ rowptr,
                                             const int* __restrict__ csr_src,
                                             const float* __restrict__ al_s,
                                             const float* __restrict__ al_d,
                                             const _Float16* __restrict__ h,
                                             const float* __restrict__ bias,
                                             float* __restrict__ outf,
                                             _Float16* __restrict__ outh,
                                             int n) {
  __shared__ float eps[4][64][8];
  __shared__ int ssrc[4][64];
  int tid = threadIdx.x;
  int w = tid >> 6, lane = tid & 63;
  int node = blockIdx.x * 4 + w;
  if (node >= n) return;
  int base = rowptr[node];
  int d = rowptr[node + 1] - base;
  int hh = lane >> 3, slot = lane & 7;
  float alD = al_d[node * HEADS + hh];

  float invs;
  f4 facc = {0.f, 0.f, 0.f, 0.f};
  const _Float16* hc = h + (lane << 2);

  if (d <= 64) {
    // stage leaky logits, tracking per-lane max
    float m = -1e30f;
    for (int j = slot; j < d; j += 8) {
      int s = csr_src[base + j];
      if (hh == 0) ssrc[w][j] = s;
      float e = al_s[s * HEADS + hh] + alD;
      e = (e > 0.f) ? e : 0.2f * e;
      eps[w][j][hh] = e;
      m = fmaxf(m, e);
    }
#pragma unroll
    for (int off = 4; off; off >>= 1) m = fmaxf(m, __shfl_xor(m, off));
    // exp in place + sum
    float sm = 0.f;
    for (int j = slot; j < d; j += 8) {
      float p = __expf(eps[w][j][hh] - m);
      eps[w][j][hh] = p;
      sm += p;
    }
#pragma unroll
    for (int off = 4; off; off >>= 1) sm += __shfl_xor(sm, off);
    invs = 1.f / (sm + 1e-16f);
    WAVE_SYNC();
    // gather: 2-edge unroll for load overlap
    int j = 0;
    for (; j + 2 <= d; j += 2) {
      int s0 = __builtin_amdgcn_readfirstlane(ssrc[w][j]);
      int s1 = __builtin_amdgcn_readfirstlane(ssrc[w][j + 1]);
      float p0 = eps[w][j][hh], p1 = eps[w][j + 1][hh];
      h4 v0 = *(const h4*)(hc + ((size_t)s0 << 8));
      h4 v1 = *(const h4*)(hc + ((size_t)s1 << 8));
      facc.x += p0 * (float)v0.x + p1 * (float)v1.x;
      facc.y += p0 * (float)v0.y + p1 * (float)v1.y;
      facc.z += p0 * (float)v0.z + p1 * (float)v1.z;
      facc.w += p0 * (float)v0.w + p1 * (float)v1.w;
    }
    if (j < d) {
      int s0 = __builtin_amdgcn_readfirstlane(ssrc[w][j]);
      float p0 = eps[w][j][hh];
      h4 v0 = *(const h4*)(hc + ((size_t)s0 << 8));
      facc.x += p0 * (float)v0.x;
      facc.y += p0 * (float)v0.y;
      facc.z += p0 * (float)v0.z;
      facc.w += p0 * (float)v0.w;
    }
  } else {
    // general path (rare): 2 streaming passes + chunked stage/gather
    float m = -1e30f;
    for (int j = slot; j < d; j += 8) {
      int s = csr_src[base + j];
      float e = al_s[s * HEADS + hh] + alD;
      e = (e > 0.f) ? e : 0.2f * e;
      m = fmaxf(m, e);
    }
#pragma unroll
    for (int off = 4; off; off >>= 1) m = fmaxf(m, __shfl_xor(m, off));
    float sm = 0.f;
    for (int j = slot; j < d; j += 8) {
      int s = csr_src[base + j];
      float e = al_s[s * HEADS + hh] + alD;
      e = (e > 0.f) ? e : 0.2f * e;
      sm += __expf(e - m);
    }
#pragma unroll
    for (int off = 4; off; off >>= 1) sm += __shfl_xor(sm, off);
    invs = 1.f / (sm + 1e-16f);
    for (int c0 = 0; c0 < d; c0 += 64) {
      int cn = min(64, d - c0);
      WAVE_SYNC();
      for (int j = slot; j < cn; j += 8) {
        int s = csr_src[base + c0 + j];
        if (hh == 0) ssrc[w][j] = s;
        float e = al_s[s * HEADS + hh] + alD;
        e = (e > 0.f) ? e : 0.2f * e;
        eps[w][j][hh] = __expf(e - m);
      }
      WAVE_SYNC();
      for (int j = 0; j < cn; ++j) {
        int s0 = __builtin_amdgcn_readfirstlane(ssrc[w][j]);
        float p0 = eps[w][j][hh];
        h4 v0 = *(const h4*)(hc + ((size_t)s0 << 8));
        facc.x += p0 * (float)v0.x;
        facc.y += p0 * (float)v0.y;
        facc.z += p0 * (float)v0.z;
        facc.w += p0 * (float)v0.w;
      }
    }
  }

  int c0 = lane << 2;
  float4 bv = *(const float4*)&bias[c0];
  float o0 = facc.x * invs + bv.x;
  float o1 = facc.y * invs + bv.y;
  float o2 = facc.z * invs + bv.z;
  float o3 = facc.w * invs + bv.w;
  o0 = (o0 > 0.f) ? o0 : expm1f(o0);
  o1 = (o1 > 0.f) ? o1 : expm1f(o1);
  o2 = (o2 > 0.f) ? o2 : expm1f(o2);
  o3 = (o3 > 0.f) ? o3 : expm1f(o3);
  if (F16OUT) {
    h4 o = {(_Float16)o0, (_Float16)o1, (_Float16)o2, (_Float16)o3};
    *(h4*)&outh[((size_t)node << 8) + c0] = o;
  } else {
    *(float4*)&outf[((size_t)node << 8) + c0] = make_float4(o0, o1, o2, o3);
  }
}

// ---------------- launch ----------------

extern "C" void kernel_launch(void* const* d_in, const int* in_sizes, int n_in,
                              void* d_out, int out_size, void* d_ws, size_t ws_size,
                              hipStream_t stream) {
  const float* x   = (const float*)d_in[0];
  const int*   ei  = (const int*)d_in[1];
  const float* W1  = (const float*)d_in[2];
  const float* a1s = (const float*)d_in[3];
  const float* a1d = (const float*)d_in[4];
  const float* b1  = (const float*)d_in[5];
  const float* W2  = (const float*)d_in[6];
  const float* a2s = (const float*)d_in[7];
  const float* a2d = (const float*)d_in[8];
  const float* b2  = (const float*)d_in[9];

  int n  = in_sizes[0] / 128;   // 50000
  int Et = in_sizes[1] / 2;     // 850000
  const int* srcp = ei;
  const int* dstp = ei + Et;

  char* ws = (char*)d_ws;
  auto alloc = [&](size_t bytes) {
    char* p = ws;
    ws += (bytes + 255) & ~(size_t)255;
    return p;
  };
  _Float16* xh     = (_Float16*)alloc((size_t)n * 128 * 2);
  _Float16* hbuf   = (_Float16*)alloc((size_t)n * F * 2);
  _Float16* Wt1    = (_Float16*)alloc((size_t)128 * F * 2);
  _Float16* Wt2    = (_Float16*)alloc((size_t)F * F * 2);
  float*    als    = (float*)alloc((size_t)n * HEADS * 4);
  float*    ald    = (float*)alloc((size_t)n * HEADS * 4);
  int*      deg    = (int*)alloc((size_t)n * 4);
  int*      fill   = (int*)alloc((size_t)n * 4);
  int*      rowptr = (int*)alloc((size_t)(n + 1) * 4);
  int*      bsum   = (int*)alloc(64 * 4);
  int*      boff   = (int*)alloc(64 * 4);
  int*      csr    = (int*)alloc((size_t)Et * 4);
  _Float16* out1h  = (_Float16*)d_out;  // layer-1 fp16 staged in d_out
  float*    outF   = (float*)d_out;

  hipMemsetAsync(deg, 0, (size_t)n * 4, stream);
  hipMemsetAsync(fill, 0, (size_t)n * 4, stream);

  k_cvt<<<(n * 128 / 4 + 255) / 256, 256, 0, stream>>>(x, xh, n * 128);
  k_cvt_wt<<<128, 256, 0, stream>>>(W1, Wt1, 128);
  k_cvt_wt<<<256, 256, 0, stream>>>(W2, Wt2, 256);

  int eb = (Et + 255) / 256;
  k_hist<<<eb, 256, 0, stream>>>(dstp, Et, deg);
  int nb = (n + 1023) / 1024;
  k_scan1<<<nb, 1024, 0, stream>>>(deg, n, rowptr, bsum);
  k_scan2<<<1, 64, 0, stream>>>(bsum, nb, boff);
  k_scan3<<<(n + 255) / 256, 256, 0, stream>>>(n, Et, rowptr, boff);
  k_fill<<<eb, 256, 0, stream>>>(srcp, dstp, Et, rowptr, fill, csr);

  dim3 gg((n + 63) / 64, 4);
  int ab = (n + 3) / 4;
  // layer 1
  k_gemm<<<gg, 256, 0, stream>>>(xh, Wt1, hbuf, a1s, a1d, als, ald, n, 128);
  k_agg<true><<<ab, 256, 0, stream>>>(rowptr, csr, als, ald, hbuf, b1, nullptr, out1h, n);
  // layer 2
  k_gemm<<<gg, 256, 0, stream>>>(out1h, Wt2, hbuf, a2s, a2d, als, ald, n, 256);
  k_agg<false><<<ab, 256, 0, stream>>>(rowptr, csr, als, ald, hbuf, b2, outF, nullptr, n);
}